// Round 1
// baseline (1890.286 us; speedup 1.0000x reference)
//
#include <hip/hip_runtime.h>

#define NN     100000
#define NB     1563          // ceil(100000 / 64)
#define LN_EPS 1e-5f
#define SLOPE  0.01f

typedef __bf16 bf16x8 __attribute__((ext_vector_type(8)));
typedef float  f32x4  __attribute__((ext_vector_type(4)));
typedef unsigned short u16;
typedef unsigned int   u32;

union Pack8 { uint4 u4; bf16x8 bf; u16 s[8]; };

__device__ __forceinline__ u16 f2bf(float x){
    u32 b = __float_as_uint(x);
    b += 0x7fffu + ((b >> 16) & 1u);
    return (u16)(b >> 16);
}
__device__ __forceinline__ float bf2f(u32 s){
    return __uint_as_float(s << 16);
}

// Pack w[1024][1024] fp32 (row = output col i, inner = k) into bf16 B-fragment
// order: Wp[k>>5][i][k&31], so a B-frag load for (col,kstep) is one dwordx4:
// uint4 index = (kstep*1024 + col)*4 + quad.
__global__ __launch_bounds__(1024) void prep_weights(
    const float* __restrict__ wa, const float* __restrict__ wb,
    const float* __restrict__ wc, const float* __restrict__ wd,
    u16* __restrict__ dst)
{
    int m = blockIdx.y;
    const float* src = (m==0)? wa : (m==1)? wb : (m==2)? wc : wd;
    u16* d = dst + (size_t)m * (1024u*1024u);
    int tid = blockIdx.x * blockDim.x + threadIdx.x;   // 0..131071
    int sub = tid & 3;
    int row = (tid >> 2) & 1023;
    int kb  = tid >> 12;                               // 0..31
    const float4* s4 = (const float4*)(src + row*1024 + kb*32 + sub*8);
    float4 a = s4[0], b = s4[1];
    Pack8 p;
    p.s[0]=f2bf(a.x); p.s[1]=f2bf(a.y); p.s[2]=f2bf(a.z); p.s[3]=f2bf(a.w);
    p.s[4]=f2bf(b.x); p.s[5]=f2bf(b.y); p.s[6]=f2bf(b.z); p.s[7]=f2bf(b.w);
    ((uint4*)d)[(kb*1024 + row)*4 + sub] = p.u4;
}

// One 32-col strip of the 64x1024 GEMM: acc[ct][rt], ct over 2 col-tiles,
// rt over 4 row-tiles (nodes). A from LDS (K-packed), B from packed weights.
template<int MDIM>
__device__ __forceinline__ void gemm_strip(
    const u16* __restrict__ Wp, const u16* xs,
    int C0, int lane15, int q, f32x4 acc[2][4])
{
    const uint4* bb = (const uint4*)Wp + (C0 + lane15)*4 + q;
    const uint4* ab = (const uint4*)xs + q*64 + lane15;
    #pragma unroll
    for (int ct=0; ct<2; ++ct)
      #pragma unroll
      for (int rt=0; rt<4; ++rt)
        acc[ct][rt] = (f32x4){0.f,0.f,0.f,0.f};
    #pragma unroll 4
    for (int ks=0; ks<32; ++ks){
        Pack8 b0, b1, a0, a1, a2, a3;
        b0.u4 = bb[ks*4096];
        b1.u4 = bb[ks*4096 + 64];
        a0.u4 = ab[ks*256];
        a1.u4 = ab[ks*256 + 16];
        a2.u4 = ab[ks*256 + 32];
        a3.u4 = ab[ks*256 + 48];
        acc[0][0] = __builtin_amdgcn_mfma_f32_16x16x32_bf16(a0.bf, b0.bf, acc[0][0], 0,0,0);
        acc[0][1] = __builtin_amdgcn_mfma_f32_16x16x32_bf16(a1.bf, b0.bf, acc[0][1], 0,0,0);
        acc[0][2] = __builtin_amdgcn_mfma_f32_16x16x32_bf16(a2.bf, b0.bf, acc[0][2], 0,0,0);
        acc[0][3] = __builtin_amdgcn_mfma_f32_16x16x32_bf16(a3.bf, b0.bf, acc[0][3], 0,0,0);
        acc[1][0] = __builtin_amdgcn_mfma_f32_16x16x32_bf16(a0.bf, b1.bf, acc[1][0], 0,0,0);
        acc[1][1] = __builtin_amdgcn_mfma_f32_16x16x32_bf16(a1.bf, b1.bf, acc[1][1], 0,0,0);
        acc[1][2] = __builtin_amdgcn_mfma_f32_16x16x32_bf16(a2.bf, b1.bf, acc[1][2], 0,0,0);
        acc[1][3] = __builtin_amdgcn_mfma_f32_16x16x32_bf16(a3.bf, b1.bf, acc[1][3], 0,0,0);
    }
}

// Fully fused: gram -> LN1 -> lrelu -> GEMM1 -> LN2 -> lrelu -> GEMM2(+bias)
// -> softmax(32) -> attn @ v. Block = 64 nodes, 16 waves.
// LDS: xs 128KB (bf16 activations, K-packed) + stats 512B + vbuf (v tile).
template<int MDIM>
__global__ __launch_bounds__(1024) void gal_fused(
    const float* __restrict__ f,
    const float* __restrict__ ln1g, const float* __restrict__ ln1b,
    const float* __restrict__ ln2g, const float* __restrict__ ln2b,
    const float* __restrict__ b2,
    const u16* __restrict__ Wp1, const u16* __restrict__ Wp2,
    float* __restrict__ outp)
{
    extern __shared__ char smem[];
    u16*   xs    = (u16*)smem;                     // 64*1024 bf16 = 131072 B
    float* stats = (float*)(smem + 131072);        // 64 nodes * {sum, sumsq}
    float* vbuf  = (float*)(smem + 131072 + 512);  // 64*32*MDIM fp32

    const int tid    = threadIdx.x;
    const int lane   = tid & 63;
    const int wv     = tid >> 6;        // wave 0..15
    const int lane15 = lane & 15;
    const int q      = lane >> 4;
    const int node0  = blockIdx.x * 64;

    // Phase 0: zero stats, stage v tile (zero-fill past N)
    if (tid < 128) stats[tid] = 0.f;
    {
        const int vcount = 64*32*MDIM;
        const int gbase  = node0*32*MDIM;
        const int glim   = NN*32*MDIM;
        for (int i = tid; i < vcount; i += 1024)
            vbuf[i] = (gbase + i < glim) ? f[gbase + i] : 0.f;
    }
    __syncthreads();

    // Phase 1: gram + LN1 + lrelu -> xs (bf16, layout [k>>3][node][k&7])
    {
        const int n = tid >> 4;       // node 0..63 (16 threads per node)
        const int j = tid & 15;       // this thread owns k = j*64 .. j*64+63
        const float* vn = vbuf + n*32*MDIM;
        float va0[MDIM], va1[MDIM];
        #pragma unroll
        for (int c=0;c<MDIM;++c){ va0[c]=vn[(j*2)*MDIM+c]; va1[c]=vn[(j*2+1)*MDIM+c]; }
        float gv[64];
        #pragma unroll
        for (int b=0;b<32;++b){
            float d0=0.f, d1=0.f;
            #pragma unroll
            for (int c=0;c<MDIM;++c){ float vb = vn[b*MDIM+c]; d0 += va0[c]*vb; d1 += va1[c]*vb; }
            gv[b]=d0; gv[32+b]=d1;
        }
        float sum=0.f, ssum=0.f;
        #pragma unroll
        for (int t=0;t<64;++t){ sum += gv[t]; ssum += gv[t]*gv[t]; }
        #pragma unroll
        for (int st=1; st<16; st<<=1){ sum += __shfl_xor(sum, st); ssum += __shfl_xor(ssum, st); }
        float mu   = sum * (1.f/1024.f);
        float rstd = rsqrtf(ssum*(1.f/1024.f) - mu*mu + LN_EPS);
        #pragma unroll
        for (int jb=0;jb<8;++jb){
            Pack8 p;
            #pragma unroll
            for (int l=0;l<8;++l){
                int k = j*64 + jb*8 + l;
                float x = (gv[jb*8+l] - mu)*rstd*ln1g[k] + ln1b[k];
                x = (x >= 0.f)? x : SLOPE*x;
                p.s[l] = f2bf(x);
            }
            ((uint4*)xs)[(j*8+jb)*64 + n] = p.u4;
        }
    }
    __syncthreads();

    // Phase 2: h1 = x1 @ W1^T; per-node sum/sumsq via shfl + LDS atomics;
    // stash h1 as packed bf16 in registers. Wave wv owns strips wv, wv+16.
    u32 h1pk[2][2][4][2];
    #pragma unroll
    for (int si=0; si<2; ++si){
        const int C0 = (wv + si*16)*32;
        f32x4 acc[2][4];
        gemm_strip<MDIM>(Wp1, xs, C0, lane15, q, acc);
        float p_[16], pp_[16];
        #pragma unroll
        for (int idx=0; idx<16; ++idx){
            float h0 = acc[0][idx>>2][idx&3];
            float h1 = acc[1][idx>>2][idx&3];
            p_[idx]  = h0 + h1;
            pp_[idx] = h0*h0 + h1*h1;
        }
        #pragma unroll
        for (int st=1; st<16; st<<=1){
            #pragma unroll
            for (int idx=0; idx<16; ++idx){
                p_[idx]  += __shfl_xor(p_[idx],  st);
                pp_[idx] += __shfl_xor(pp_[idx], st);
            }
        }
        float myp=0.f, mypp=0.f; int mynode=0;
        #pragma unroll
        for (int idx=0; idx<16; ++idx){
            if (lane15 == idx){ myp=p_[idx]; mypp=pp_[idx]; mynode=(idx>>2)*16 + q*4 + (idx&3); }
        }
        atomicAdd(&stats[2*mynode],   myp);
        atomicAdd(&stats[2*mynode+1], mypp);
        #pragma unroll
        for (int ct=0; ct<2; ++ct)
          #pragma unroll
          for (int rt=0; rt<4; ++rt){
            h1pk[si][ct][rt][0] = (u32)f2bf(acc[ct][rt][0]) | ((u32)f2bf(acc[ct][rt][1])<<16);
            h1pk[si][ct][rt][1] = (u32)f2bf(acc[ct][rt][2]) | ((u32)f2bf(acc[ct][rt][3])<<16);
          }
    }
    __syncthreads();

    // Phase 3: LN2 + lrelu -> x2 into xs (same K-packed layout)
    {
        float g2c[2][2], b2c[2][2];
        #pragma unroll
        for (int si=0; si<2; ++si)
          #pragma unroll
          for (int ct=0; ct<2; ++ct){
            int col = (wv + si*16)*32 + ct*16 + lane15;
            g2c[si][ct] = ln2g[col];
            b2c[si][ct] = ln2b[col];
          }
        #pragma unroll
        for (int rt=0; rt<4; ++rt)
          #pragma unroll
          for (int rr=0; rr<4; ++rr){
            int node = rt*16 + q*4 + rr;
            float mu   = stats[2*node]*(1.f/1024.f);
            float rstd = rsqrtf(stats[2*node+1]*(1.f/1024.f) - mu*mu + LN_EPS);
            #pragma unroll
            for (int si=0; si<2; ++si)
              #pragma unroll
              for (int ct=0; ct<2; ++ct){
                u32 u = h1pk[si][ct][rt][rr>>1];
                float h = bf2f((rr&1)? (u>>16) : (u & 0xffffu));
                float x = (h - mu)*rstd*g2c[si][ct] + b2c[si][ct];
                x = (x >= 0.f)? x : SLOPE*x;
                int col = (wv + si*16)*32 + ct*16 + lane15;
                xs[(col>>3)*512 + node*8 + (col&7)] = f2bf(x);
              }
          }
    }
    __syncthreads();

    // Phase 4: h2 = x2 @ W2^T + b2; softmax over b (the 32 cols of this
    // strip = one 'a' group); out[n,a,c] = sum_b attn*v — all in regs/shfl.
    #pragma unroll
    for (int si=0; si<2; ++si){
        const int aidx = wv + si*16;
        const int C0 = aidx*32;
        f32x4 acc[2][4];
        gemm_strip<MDIM>(Wp2, xs, C0, lane15, q, acc);
        float bb0 = b2[C0 + lane15];
        float bb1 = b2[C0 + 16 + lane15];
        #pragma unroll
        for (int idx=0; idx<16; ++idx){
            int rt = idx>>2, rr = idx&3;
            int node = rt*16 + q*4 + rr;
            float h0 = acc[0][rt][rr] + bb0;   // b = lane15
            float h1 = acc[1][rt][rr] + bb1;   // b = 16 + lane15
            float mx = fmaxf(h0, h1);
            #pragma unroll
            for (int st=1; st<16; st<<=1) mx = fmaxf(mx, __shfl_xor(mx, st));
            float e0 = __expf(h0 - mx);
            float e1 = __expf(h1 - mx);
            float sm = e0 + e1;
            #pragma unroll
            for (int st=1; st<16; st<<=1) sm += __shfl_xor(sm, st);
            float inv = 1.f / sm;
            int ng = node0 + node;
            #pragma unroll
            for (int c=0; c<MDIM; ++c){
                float t = e0*vbuf[(node*32 + lane15)*MDIM + c]
                        + e1*vbuf[(node*32 + 16 + lane15)*MDIM + c];
                #pragma unroll
                for (int st=1; st<16; st<<=1) t += __shfl_xor(t, st);
                if (lane15 == idx && ng < NN)
                    outp[((size_t)ng*32 + aidx)*MDIM + c] = t*inv;
            }
        }
    }
}

extern "C" void kernel_launch(void* const* d_in, const int* in_sizes, int n_in,
                              void* d_out, int out_size, void* d_ws, size_t ws_size,
                              hipStream_t stream)
{
    const float* f0    = (const float*)d_in[0];
    const float* f1    = (const float*)d_in[1];
    const float* ln1g0 = (const float*)d_in[2];
    const float* ln1b0 = (const float*)d_in[3];
    const float* w1_0  = (const float*)d_in[4];
    const float* ln2g0 = (const float*)d_in[5];
    const float* ln2b0 = (const float*)d_in[6];
    const float* w2_0  = (const float*)d_in[7];
    const float* b2_0  = (const float*)d_in[8];
    const float* ln1g1 = (const float*)d_in[9];
    const float* ln1b1 = (const float*)d_in[10];
    const float* w1_1  = (const float*)d_in[11];
    const float* ln2g1 = (const float*)d_in[12];
    const float* ln2b1 = (const float*)d_in[13];
    const float* w2_1  = (const float*)d_in[14];
    const float* b2_1  = (const float*)d_in[15];
    float* out = (float*)d_out;
    u16* wp = (u16*)d_ws;    // 4 packed matrices x 2 MB = 8 MB scratch

    const int smem1 = 131072 + 512 + 64*32*1*4;   // 139776
    const int smem3 = 131072 + 512 + 64*32*3*4;   // 156160
    (void)hipFuncSetAttribute(reinterpret_cast<const void*>(&gal_fused<1>),
                              hipFuncAttributeMaxDynamicSharedMemorySize, smem1);
    (void)hipFuncSetAttribute(reinterpret_cast<const void*>(&gal_fused<3>),
                              hipFuncAttributeMaxDynamicSharedMemorySize, smem3);

    prep_weights<<<dim3(128,4), 1024, 0, stream>>>(w1_0, w2_0, w1_1, w2_1, wp);
    gal_fused<1><<<NB, 1024, smem1, stream>>>(f0, ln1g0, ln1b0, ln2g0, ln2b0, b2_0,
                                              wp,            wp + 1048576, out);
    gal_fused<3><<<NB, 1024, smem3, stream>>>(f1, ln1g1, ln1b1, ln2g1, ln2b1, b2_1,
                                              wp + 2097152,  wp + 3145728, out + (size_t)NN*32);
}

// Round 2
// 1392.208 us; speedup vs baseline: 1.3578x; 1.3578x over previous
//
#include <hip/hip_runtime.h>

#define NN     100000
#define NB     1563          // ceil(100000 / 64)
#define LN_EPS 1e-5f
#define SLOPE  0.01f

typedef __bf16 bf16x8 __attribute__((ext_vector_type(8)));
typedef float  f32x4  __attribute__((ext_vector_type(4)));
typedef unsigned short u16;
typedef unsigned int   u32;

union Pack8 { uint4 u4; bf16x8 bf; u16 s[8]; };

__device__ __forceinline__ u16 f2bf(float x){
    u32 b = __float_as_uint(x);
    b += 0x7fffu + ((b >> 16) & 1u);
    return (u16)(b >> 16);
}
__device__ __forceinline__ float bf2f(u32 s){
    return __uint_as_float(s << 16);
}

// Pack w[1024][1024] fp32 (row = output col i, inner = k) into bf16 B-fragment
// order: Wp[k>>5][i][k&31]; B-frag load for (col,ks) is uint4 (ks*1024+col)*4+q.
__global__ __launch_bounds__(1024) void prep_weights(
    const float* __restrict__ wa, const float* __restrict__ wb,
    const float* __restrict__ wc, const float* __restrict__ wd,
    u16* __restrict__ dst)
{
    int m = blockIdx.y;
    const float* src = (m==0)? wa : (m==1)? wb : (m==2)? wc : wd;
    u16* d = dst + (size_t)m * (1024u*1024u);
    int tid = blockIdx.x * blockDim.x + threadIdx.x;   // 0..131071
    int sub = tid & 3;
    int row = (tid >> 2) & 1023;
    int kb  = tid >> 12;                               // 0..31
    const float4* s4 = (const float4*)(src + row*1024 + kb*32 + sub*8);
    float4 a = s4[0], b = s4[1];
    Pack8 p;
    p.s[0]=f2bf(a.x); p.s[1]=f2bf(a.y); p.s[2]=f2bf(a.z); p.s[3]=f2bf(a.w);
    p.s[4]=f2bf(b.x); p.s[5]=f2bf(b.y); p.s[6]=f2bf(b.z); p.s[7]=f2bf(b.w);
    ((uint4*)d)[(kb*1024 + row)*4 + sub] = p.u4;
}

// 64x1024 @ 1024x64-strip GEMM piece: one wave computes 4 column-tiles
// (cols wv*32..+31 and (wv+16)*32..+31) for all 64 nodes. A-frags from LDS
// (K-packed) are reused across all 4 B-frags: 16 MFMA per 4 ds_read_b128.
__device__ __forceinline__ void gemm_quad(
    const u16* __restrict__ Wp, const u16* xs,
    int wv, int lane15, int q, f32x4 acc[4][4])
{
    const uint4* bA = (const uint4*)Wp + (wv*32 + lane15)*4 + q;
    const uint4* bB = (const uint4*)Wp + ((wv+16)*32 + lane15)*4 + q;
    const uint4* ab = (const uint4*)xs + q*64 + lane15;
    #pragma unroll
    for (int ct=0; ct<4; ++ct)
      #pragma unroll
      for (int rt=0; rt<4; ++rt)
        acc[ct][rt] = (f32x4){0.f,0.f,0.f,0.f};
    #pragma unroll 2
    for (int ks=0; ks<32; ++ks){
        Pack8 b0, b1, b2, b3, a0, a1, a2, a3;
        b0.u4 = bA[ks*4096];
        b1.u4 = bA[ks*4096 + 64];
        b2.u4 = bB[ks*4096];
        b3.u4 = bB[ks*4096 + 64];
        a0.u4 = ab[ks*256];
        a1.u4 = ab[ks*256 + 16];
        a2.u4 = ab[ks*256 + 32];
        a3.u4 = ab[ks*256 + 48];
        acc[0][0] = __builtin_amdgcn_mfma_f32_16x16x32_bf16(a0.bf, b0.bf, acc[0][0], 0,0,0);
        acc[0][1] = __builtin_amdgcn_mfma_f32_16x16x32_bf16(a1.bf, b0.bf, acc[0][1], 0,0,0);
        acc[0][2] = __builtin_amdgcn_mfma_f32_16x16x32_bf16(a2.bf, b0.bf, acc[0][2], 0,0,0);
        acc[0][3] = __builtin_amdgcn_mfma_f32_16x16x32_bf16(a3.bf, b0.bf, acc[0][3], 0,0,0);
        acc[1][0] = __builtin_amdgcn_mfma_f32_16x16x32_bf16(a0.bf, b1.bf, acc[1][0], 0,0,0);
        acc[1][1] = __builtin_amdgcn_mfma_f32_16x16x32_bf16(a1.bf, b1.bf, acc[1][1], 0,0,0);
        acc[1][2] = __builtin_amdgcn_mfma_f32_16x16x32_bf16(a2.bf, b1.bf, acc[1][2], 0,0,0);
        acc[1][3] = __builtin_amdgcn_mfma_f32_16x16x32_bf16(a3.bf, b1.bf, acc[1][3], 0,0,0);
        acc[2][0] = __builtin_amdgcn_mfma_f32_16x16x32_bf16(a0.bf, b2.bf, acc[2][0], 0,0,0);
        acc[2][1] = __builtin_amdgcn_mfma_f32_16x16x32_bf16(a1.bf, b2.bf, acc[2][1], 0,0,0);
        acc[2][2] = __builtin_amdgcn_mfma_f32_16x16x32_bf16(a2.bf, b2.bf, acc[2][2], 0,0,0);
        acc[2][3] = __builtin_amdgcn_mfma_f32_16x16x32_bf16(a3.bf, b2.bf, acc[2][3], 0,0,0);
        acc[3][0] = __builtin_amdgcn_mfma_f32_16x16x32_bf16(a0.bf, b3.bf, acc[3][0], 0,0,0);
        acc[3][1] = __builtin_amdgcn_mfma_f32_16x16x32_bf16(a1.bf, b3.bf, acc[3][1], 0,0,0);
        acc[3][2] = __builtin_amdgcn_mfma_f32_16x16x32_bf16(a2.bf, b3.bf, acc[3][2], 0,0,0);
        acc[3][3] = __builtin_amdgcn_mfma_f32_16x16x32_bf16(a3.bf, b3.bf, acc[3][3], 0,0,0);
    }
}

// LDS layout (bytes):
//   [0, 131328)          : xs (bf16 activations, 131072 B) / later sbuf
//                          (fp32 h2 strips, 16 waves x 2052 floats)
//   [131328, +64*VSTR*4) : vbuf, per-node padded v rows (fp32)
//   then 512 B           : stats (64 nodes x {sum, sumsq})
template<int MDIM>
__global__ __launch_bounds__(1024, 4) void gal_fused(
    const float* __restrict__ f,
    const float* __restrict__ ln1g, const float* __restrict__ ln1b,
    const float* __restrict__ ln2g, const float* __restrict__ ln2b,
    const float* __restrict__ b2,
    const u16* __restrict__ Wp1, const u16* __restrict__ Wp2,
    float* __restrict__ outp)
{
    extern __shared__ char smem[];
    constexpr int VSTR = 32*MDIM + 4;           // padded node stride (floats)
    constexpr int SBS  = 64*32 + 4;             // sbuf per-wave stride = 2052
    u16*   xs    = (u16*)smem;
    float* sbuf  = (float*)smem;
    float* vbuf  = (float*)smem + 32832;        // 131328/4
    float* stats = (float*)smem + 32832 + 64*VSTR;

    const int tid    = threadIdx.x;
    const int lane   = tid & 63;
    const int wv     = tid >> 6;
    const int lane15 = lane & 15;
    const int q      = lane >> 4;
    const int node0  = blockIdx.x * 64;

    // ---- Phase 0: zero stats, stage v tile (padded, zero-fill past N)
    if (tid < 128) stats[tid] = 0.f;
    {
        const int gbase = node0*32*MDIM;
        for (int i = tid; i < 64*32*MDIM; i += 1024){
            int nd = i / (32*MDIM);
            int r  = i - nd*(32*MDIM);
            float val = (gbase + i < NN*32*MDIM) ? f[gbase + i] : 0.f;
            vbuf[nd*VSTR + r] = val;
        }
    }
    __syncthreads();

    // ---- Phase 1: gram + LN1 + lrelu -> xs (bf16, [k>>3][node][k&7])
    // Recompute dots in the pack pass instead of keeping 64 floats live.
    {
        const int n = tid >> 4;          // node
        const int j = tid & 15;          // owns k = j*64 .. j*64+63
        const float* vn = vbuf + n*VSTR;
        float va[2][MDIM];
        #pragma unroll
        for (int c=0;c<MDIM;++c){ va[0][c]=vn[(j*2)*MDIM+c]; va[1][c]=vn[(j*2+1)*MDIM+c]; }
        float sum=0.f, ssum=0.f;
        #pragma unroll
        for (int b=0;b<32;++b){
            float d0=0.f, d1=0.f;
            #pragma unroll
            for (int c=0;c<MDIM;++c){ float vb = vn[b*MDIM+c]; d0 += va[0][c]*vb; d1 += va[1][c]*vb; }
            sum += d0+d1; ssum += d0*d0 + d1*d1;
        }
        #pragma unroll
        for (int st=1; st<16; st<<=1){ sum += __shfl_xor(sum, st); ssum += __shfl_xor(ssum, st); }
        float mu   = sum * (1.f/1024.f);
        float rstd = rsqrtf(ssum*(1.f/1024.f) - mu*mu + LN_EPS);
        #pragma unroll
        for (int jb=0;jb<8;++jb){
            Pack8 p;
            const int ai = jb >> 2;
            #pragma unroll
            for (int l=0;l<8;++l){
                int b = (jb*8+l) & 31;
                float d = 0.f;
                #pragma unroll
                for (int c=0;c<MDIM;++c) d += va[ai][c]*vn[b*MDIM+c];
                int k = j*64 + jb*8 + l;
                float x = (d - mu)*rstd*ln1g[k] + ln1b[k];
                x = (x >= 0.f)? x : SLOPE*x;
                p.s[l] = f2bf(x);
            }
            ((uint4*)xs)[(j*8+jb)*64 + n] = p.u4;
        }
    }
    __syncthreads();

    // ---- Phase 2: h1 = x1 @ W1^T (all 4 col-tiles per wave); stats via
    // multi-value fold-tree + one atomic pair; h1 stashed bf16 in regs.
    u32 h1pk[4][4][2];
    {
        f32x4 acc[4][4];
        gemm_quad(Wp1, xs, wv, lane15, q, acc);
        float p_[16], pp_[16];
        #pragma unroll
        for (int idx=0; idx<16; ++idx){
            int rt = idx>>2, rr = idx&3;
            float s=0.f, s2=0.f;
            #pragma unroll
            for (int ct=0; ct<4; ++ct){
                float h = acc[ct][rt][rr];
                s += h; s2 += h*h;
            }
            p_[idx] = s; pp_[idx] = s2;
        }
        // fold-tree: after the loop, lane15==l holds totals for idx l in [0]
        #pragma unroll
        for (int m=8; m>=1; m>>=1){
            const bool hi = (lane15 & m) != 0;
            #pragma unroll
            for (int i=0; i<m; ++i){
                float sp = hi ? p_[i]  : p_[i+m];
                float kp = hi ? p_[i+m]  : p_[i];
                p_[i]  = kp + __shfl_xor(sp, m);
                float sq = hi ? pp_[i] : pp_[i+m];
                float kq = hi ? pp_[i+m] : pp_[i];
                pp_[i] = kq + __shfl_xor(sq, m);
            }
        }
        {
            int nd = (lane15>>2)*16 + q*4 + (lane15&3);
            atomicAdd(&stats[2*nd],   p_[0]);
            atomicAdd(&stats[2*nd+1], pp_[0]);
        }
        #pragma unroll
        for (int ct=0; ct<4; ++ct)
          #pragma unroll
          for (int rt=0; rt<4; ++rt){
            h1pk[ct][rt][0] = (u32)f2bf(acc[ct][rt][0]) | ((u32)f2bf(acc[ct][rt][1])<<16);
            h1pk[ct][rt][1] = (u32)f2bf(acc[ct][rt][2]) | ((u32)f2bf(acc[ct][rt][3])<<16);
          }
    }
    __syncthreads();

    // ---- Phase 3: LN2 + lrelu -> x2 into xs (same K-packed layout)
    {
        float g2c[4], b2c[4];
        #pragma unroll
        for (int ct=0; ct<4; ++ct){
            int col = (wv + (ct>>1)*16)*32 + (ct&1)*16 + lane15;
            g2c[ct] = ln2g[col];
            b2c[ct] = ln2b[col];
        }
        #pragma unroll
        for (int rt=0; rt<4; ++rt)
          #pragma unroll
          for (int rr=0; rr<4; ++rr){
            int nd = rt*16 + q*4 + rr;
            float mu   = stats[2*nd]*(1.f/1024.f);
            float rstd = rsqrtf(stats[2*nd+1]*(1.f/1024.f) - mu*mu + LN_EPS);
            #pragma unroll
            for (int ct=0; ct<4; ++ct){
                u32 u = h1pk[ct][rt][rr>>1];
                float h = bf2f((rr&1)? (u>>16) : (u & 0xffffu));
                float x = (h - mu)*rstd*g2c[ct] + b2c[ct];
                x = (x >= 0.f)? x : SLOPE*x;
                int col = (wv + (ct>>1)*16)*32 + (ct&1)*16 + lane15;
                xs[(col>>3)*512 + nd*8 + (col&7)] = f2bf(x);
            }
          }
    }
    __syncthreads();

    // ---- Phase 4: h2 = x2 @ W2^T + b2; stage each a-strip (fp32) into the
    // retired xs region; then one thread per (node, a): softmax + attn @ v.
    {
        f32x4 acc[4][4];
        gemm_quad(Wp2, xs, wv, lane15, q, acc);
        float bias[4];
        #pragma unroll
        for (int ct=0; ct<4; ++ct)
            bias[ct] = b2[(wv + (ct>>1)*16)*32 + (ct&1)*16 + lane15];
        __syncthreads();   // all xs reads complete before sbuf overwrite

        #pragma unroll
        for (int si=0; si<2; ++si){
            // stage strip a = wv + si*16 : sbuf[wv][node][b]
            #pragma unroll
            for (int ctl=0; ctl<2; ++ctl){
                const int ct = si*2 + ctl;
                #pragma unroll
                for (int rt=0; rt<4; ++rt)
                  #pragma unroll
                  for (int rr=0; rr<4; ++rr){
                    int nd = rt*16 + q*4 + rr;
                    sbuf[wv*SBS + nd*32 + ctl*16 + lane15] = acc[ct][rt][rr] + bias[ct];
                  }
            }
            __syncthreads();
            // consume: thread -> (node = tid>>4, a = (tid&15) + si*16)
            {
                const int nd  = tid >> 4;
                const int a15 = tid & 15;
                const float* hp = sbuf + a15*SBS + nd*32;
                float e[32];
                #pragma unroll
                for (int r=0;r<8;++r){
                    float4 v4 = ((const float4*)hp)[r];
                    e[4*r]=v4.x; e[4*r+1]=v4.y; e[4*r+2]=v4.z; e[4*r+3]=v4.w;
                }
                float mx = e[0];
                #pragma unroll
                for (int b=1;b<32;++b) mx = fmaxf(mx, e[b]);
                float sm = 0.f;
                #pragma unroll
                for (int b=0;b<32;++b){ e[b] = __expf(e[b]-mx); sm += e[b]; }
                float inv = 1.f / sm;
                float oacc[MDIM];
                #pragma unroll
                for (int c=0;c<MDIM;++c) oacc[c]=0.f;
                const float4* vr = (const float4*)(vbuf + nd*VSTR);
                #pragma unroll
                for (int r=0; r<8*MDIM; ++r){
                    float4 v4 = vr[r];
                    #pragma unroll
                    for (int t=0;t<4;++t){
                        const int fi = 4*r+t;
                        const int b  = fi/MDIM;
                        const int c  = fi - b*MDIM;
                        float comp = (t==0)?v4.x:(t==1)?v4.y:(t==2)?v4.z:v4.w;
                        oacc[c] += e[b]*comp;
                    }
                }
                int ng = node0 + nd;
                if (ng < NN){
                    #pragma unroll
                    for (int c=0;c<MDIM;++c)
                        outp[((size_t)ng*32 + a15 + si*16)*MDIM + c] = oacc[c]*inv;
                }
            }
            if (si==0) __syncthreads();   // WAR on sbuf before next stage
        }
    }
}

extern "C" void kernel_launch(void* const* d_in, const int* in_sizes, int n_in,
                              void* d_out, int out_size, void* d_ws, size_t ws_size,
                              hipStream_t stream)
{
    const float* f0    = (const float*)d_in[0];
    const float* f1    = (const float*)d_in[1];
    const float* ln1g0 = (const float*)d_in[2];
    const float* ln1b0 = (const float*)d_in[3];
    const float* w1_0  = (const float*)d_in[4];
    const float* ln2g0 = (const float*)d_in[5];
    const float* ln2b0 = (const float*)d_in[6];
    const float* w2_0  = (const float*)d_in[7];
    const float* b2_0  = (const float*)d_in[8];
    const float* ln1g1 = (const float*)d_in[9];
    const float* ln1b1 = (const float*)d_in[10];
    const float* w1_1  = (const float*)d_in[11];
    const float* ln2g1 = (const float*)d_in[12];
    const float* ln2b1 = (const float*)d_in[13];
    const float* w2_1  = (const float*)d_in[14];
    const float* b2_1  = (const float*)d_in[15];
    float* out = (float*)d_out;
    u16* wp = (u16*)d_ws;    // 4 packed matrices x 2 MB = 8 MB scratch

    const int smem1 = (32832 + 64*(32*1+4) + 128)*4;   // 141056
    const int smem3 = (32832 + 64*(32*3+4) + 128)*4;   // 157440
    (void)hipFuncSetAttribute(reinterpret_cast<const void*>(&gal_fused<1>),
                              hipFuncAttributeMaxDynamicSharedMemorySize, smem1);
    (void)hipFuncSetAttribute(reinterpret_cast<const void*>(&gal_fused<3>),
                              hipFuncAttributeMaxDynamicSharedMemorySize, smem3);

    prep_weights<<<dim3(128,4), 1024, 0, stream>>>(w1_0, w2_0, w1_1, w2_1, wp);
    gal_fused<1><<<NB, 1024, smem1, stream>>>(f0, ln1g0, ln1b0, ln2g0, ln2b0, b2_0,
                                              wp,            wp + 1048576, out);
    gal_fused<3><<<NB, 1024, smem3, stream>>>(f1, ln1g1, ln1b1, ln2g1, ln2b1, b2_1,
                                              wp + 2097152,  wp + 3145728, out + (size_t)NN*32);
}